// Round 2
// baseline (1204.491 us; speedup 1.0000x reference)
//
#include <hip/hip_runtime.h>
#include <hip/hip_bf16.h>

#define NN 64
#define CI 128
#define HD 128
#define KC 5

__device__ __forceinline__ float us2f(unsigned short u) {
    union { unsigned i; float f; } v; v.i = ((unsigned)u) << 16; return v.f;
}
__device__ __forceinline__ float ulo(unsigned u) {
    union { unsigned i; float f; } v; v.i = u << 16; return v.f;
}
__device__ __forceinline__ float uhi(unsigned u) {
    union { unsigned i; float f; } v; v.i = u & 0xFFFF0000u; return v.f;
}
__device__ __forceinline__ unsigned short f2us(float f) {
    __hip_bfloat16 h = __float2bfloat16(f);
    return *reinterpret_cast<unsigned short*>(&h);
}
__device__ __forceinline__ unsigned pack2(float a, float b) {
    return ((unsigned)f2us(b) << 16) | (unsigned)f2us(a);
}

extern "C" __global__ __launch_bounds__(256, 2)
void diffpool_kernel(const float* __restrict__ x,
                     const int* __restrict__ ei,
                     const float* __restrict__ Wp,
                     const float* __restrict__ bp,
                     const float* __restrict__ W1,
                     const float* __restrict__ b1,
                     const float* __restrict__ W2,
                     const float* __restrict__ b2,
                     const float* __restrict__ Wl,
                     const float* __restrict__ bl,
                     float* __restrict__ out,
                     int E, int epg)
{
    __shared__ __attribute__((aligned(16))) unsigned short sx[NN][CI];   // x tile -> bf16 bits
    __shared__ __attribute__((aligned(16))) unsigned short sh[NN][HD];   // H1 = x@W1, bf16 bits
    __shared__ int   sadj[NN][NN];      // edge counts (int) then float bits in place
    __shared__ float sS0[NN][KC];       // S0 = x@Wp, then Sd = d*S0
    __shared__ float sS [NN][KC];       // softmaxed s
    __shared__ float sdl[NN][KC];       // s * d (row-scaled)
    __shared__ float sd [NN];           // d = rsqrt(clip(deg,1))
    __shared__ float sU [NN][KC];       // U = adj @ s
    __shared__ float sT [KC][NN];       // T = s^T A_n
    __shared__ float scol[KC];          // colsum of s
    __shared__ float sadjp[KC][KC];     // adj_p1
    __shared__ float sd2[KC];
    __shared__ float scoef[KC];
    __shared__ float sxp [KC][HD];      // x_p1
    __shared__ float sxw2[KC][HD];      // x_p1 @ W2
    __shared__ float sred[HD];

    const int t = threadIdx.x;
    const int g = blockIdx.x;

    // ---- stage x tile: 64x128 f32 (32 KB in HBM) -> bf16 in LDS; zero adj ----
    {
        const float4* srcp = reinterpret_cast<const float4*>(x + (size_t)g * NN * CI);
        uint2* dstp = reinterpret_cast<uint2*>(&sx[0][0]);   // 4 bf16 per uint2
        #pragma unroll
        for (int i = 0; i < 8; ++i) {
            float4 v = srcp[t + 256 * i];
            uint2 p;
            p.x = pack2(v.x, v.y);
            p.y = pack2(v.z, v.w);
            dstp[t + 256 * i] = p;
        }
        int* ap = &sadj[0][0];
        #pragma unroll
        for (int i = 0; i < 16; ++i) ap[t + 256 * i] = 0;
    }
    __syncthreads();

    // ---- build adjacency via LDS int atomics ----
    {
        const int base = g * epg;
        for (int j = t; j < epg; j += 256) {
            int sn = ei[base + j];
            int dn = ei[E + base + j];
            atomicAdd(&sadj[sn & 63][dn & 63], 1);
        }
    }
    __syncthreads();
    // in-place int count -> float bits
    {
        int* ap = &sadj[0][0];
        #pragma unroll
        for (int i = 0; i < 16; ++i) {
            int idx = t + 256 * i;
            ap[idx] = __float_as_int((float)ap[idx]);
        }
    }
    __syncthreads();
    #define ADJF(n, m) __int_as_float(sadj[n][m])

    // ---- H1 = x @ W1 (8x4 register tile, fp32 accum, store bf16) ----
    {
        const int rt = t >> 5;   // 0..7  -> rows rt*8..rt*8+7
        const int ct = t & 31;   // 0..31 -> cols ct*4..ct*4+3
        float acc[8][4];
        #pragma unroll
        for (int i = 0; i < 8; ++i)
            #pragma unroll
            for (int j = 0; j < 4; ++j) acc[i][j] = 0.f;
        for (int k = 0; k < CI; k += 2) {
            const float4 wa = *reinterpret_cast<const float4*>(W1 + (k    ) * HD + ct * 4);
            const float4 wb = *reinterpret_cast<const float4*>(W1 + (k + 1) * HD + ct * 4);
            float w0[4]  = { wa.x, wa.y, wa.z, wa.w };
            float w1r[4] = { wb.x, wb.y, wb.z, wb.w };
            #pragma unroll
            for (int i = 0; i < 8; ++i) {
                unsigned xp = *reinterpret_cast<const unsigned*>(&sx[rt * 8 + i][k]);
                float xa = ulo(xp), xb = uhi(xp);
                #pragma unroll
                for (int j = 0; j < 4; ++j)
                    acc[i][j] += xa * w0[j] + xb * w1r[j];
            }
        }
        #pragma unroll
        for (int i = 0; i < 8; ++i)
            #pragma unroll
            for (int j = 0; j < 4; ++j)
                sh[rt * 8 + i][ct * 4 + j] = f2us(acc[i][j]);
    }
    // ---- S0 = x @ Wp (64x5) ----
    for (int o = t; o < NN * KC; o += 256) {
        int n = o / KC, c = o % KC;
        float a = 0.f;
        for (int k = 0; k < CI; ++k) a += us2f(sx[n][k]) * Wp[k * KC + c];
        sS0[n][c] = a;
    }
    __syncthreads();

    // ---- degrees: d = rsqrt(max(rowsum(adj_l), 1)), adj_l = adj with diag=1 ----
    if (t < NN) {
        float s_ = 0.f;
        for (int m = 0; m < NN; ++m) s_ += ADJF(t, m);
        s_ += 1.0f - ADJF(t, t);
        sd[t] = rsqrtf(fmaxf(s_, 1.0f));
    }
    __syncthreads();
    // Sd[m][j] = d[m] * S0[m][j] in place
    for (int o = t; o < NN * KC; o += 256) {
        int m = o / KC, j = o % KC;
        sS0[m][j] *= sd[m];
    }
    __syncthreads();

    // ---- s_pre = d[n]*(adj_l @ Sd) + bp ; softmax over 5 ----
    if (t < NN) {
        const int n = t;
        float acc[KC] = {0, 0, 0, 0, 0};
        for (int m = 0; m < NN; ++m) {
            float a = (m == n) ? 1.0f : ADJF(n, m);
            #pragma unroll
            for (int j = 0; j < KC; ++j) acc[j] += a * sS0[m][j];
        }
        const float dn = sd[n];
        float mx = -1e30f;
        #pragma unroll
        for (int j = 0; j < KC; ++j) {
            acc[j] = acc[j] * dn + bp[j];
            mx = fmaxf(mx, acc[j]);
        }
        float sum = 0.f;
        #pragma unroll
        for (int j = 0; j < KC; ++j) { acc[j] = expf(acc[j] - mx); sum += acc[j]; }
        float inv = 1.0f / sum;
        #pragma unroll
        for (int j = 0; j < KC; ++j) {
            float sv = acc[j] * inv;
            sS[n][j] = sv;
            sdl[n][j] = sv * dn;
        }
    }
    __syncthreads();

    // ---- U = adj @ s (raw adj) ; colsum(s) ----
    if (t < NN) {
        const int n = t;
        float acc[KC] = {0, 0, 0, 0, 0};
        for (int m = 0; m < NN; ++m) {
            float a = ADJF(n, m);
            #pragma unroll
            for (int l = 0; l < KC; ++l) acc[l] += a * sS[m][l];
        }
        #pragma unroll
        for (int l = 0; l < KC; ++l) sU[n][l] = acc[l];
    } else if (t < NN + KC) {
        const int k = t - NN;
        float c_ = 0.f;
        for (int n = 0; n < NN; ++n) c_ += sS[n][k];
        scol[k] = c_;
    }
    __syncthreads();

    // ---- adj_p1 = s^T U ; T = s^T A_n (with diag-corrected adj_l) ----
    if (t < KC * KC) {
        int k = t / KC, l = t % KC;
        float a = 0.f;
        for (int n = 0; n < NN; ++n) a += sS[n][k] * sU[n][l];
        sadjp[k][l] = a;
    }
    for (int o = t; o < KC * NN; o += 256) {
        int k = o >> 6, m = o & 63;
        float a = 0.f;
        for (int n = 0; n < NN; ++n) a += sdl[n][k] * ADJF(n, m);
        a += sdl[m][k] * (1.0f - ADJF(m, m));
        sT[k][m] = sd[m] * a;
    }
    __syncthreads();

    // ---- x_p1 = T @ H1 + colsum(s) * b1 ; d2 from adj_p1 ----
    for (int o = t; o < KC * HD; o += 256) {
        int k = o >> 7, c = o & 127;
        float a = 0.f;
        for (int m = 0; m < NN; ++m) a += sT[k][m] * us2f(sh[m][c]);
        sxp[k][c] = a + scol[k] * b1[c];
    }
    if (t < KC) {
        float s_ = 0.f;
        #pragma unroll
        for (int l = 0; l < KC; ++l) s_ += sadjp[t][l];
        s_ += 1.0f - sadjp[t][t];
        sd2[t] = rsqrtf(fmaxf(s_, 1.0f));
    }
    __syncthreads();

    // ---- XW2 = x_p1 @ W2 ; coef[l] = d2[l]*sum_k d2[k]*adjl2[k][l] ----
    for (int o = t; o < KC * HD; o += 256) {
        int k = o >> 7, c = o & 127;
        float a = 0.f;
        for (int h = 0; h < HD; ++h) a += sxp[k][h] * W2[h * HD + c];
        sxw2[k][c] = a;
    }
    if (t < KC) {
        const int l = t;
        float a = 0.f;
        #pragma unroll
        for (int k = 0; k < KC; ++k) a += sd2[k] * sadjp[k][l];
        a += sd2[l] * (1.0f - sadjp[l][l]);
        scoef[l] = sd2[l] * a;
    }
    __syncthreads();

    // ---- pooled[c] = sum_l coef[l]*XW2[l][c] + 5*b2[c]; dot with W_lin ----
    if (t < HD) {
        float p = 0.f;
        #pragma unroll
        for (int l = 0; l < KC; ++l) p += scoef[l] * sxw2[l][t];
        p += 5.0f * b2[t];
        sred[t] = p * Wl[t];
    }
    __syncthreads();
    if (t == 0) {
        float a = 0.f;
        for (int c = 0; c < HD; ++c) a += sred[c];
        out[g] = a + bl[0];
    }
}

extern "C" void kernel_launch(void* const* d_in, const int* in_sizes, int n_in,
                              void* d_out, int out_size, void* d_ws, size_t ws_size,
                              hipStream_t stream) {
    const float* x  = (const float*)d_in[0];
    const int*   ei = (const int*)d_in[1];
    // d_in[2] = batch (implied by layout; unused)
    const float* Wp = (const float*)d_in[3];
    const float* bp = (const float*)d_in[4];
    const float* W1 = (const float*)d_in[5];
    const float* b1 = (const float*)d_in[6];
    const float* W2 = (const float*)d_in[7];
    const float* b2 = (const float*)d_in[8];
    const float* Wl = (const float*)d_in[9];
    const float* bl = (const float*)d_in[10];
    float* out = (float*)d_out;

    const int B = out_size;             // 8192 graphs
    const int E = in_sizes[1] / 2;      // edge_index is [2, E]
    const int epg = E / B;              // 512 edges per graph

    diffpool_kernel<<<B, 256, 0, stream>>>(x, ei, Wp, bp, W1, b1, W2, b2, Wl, bl,
                                           out, E, epg);
}

// Round 3
// 618.729 us; speedup vs baseline: 1.9467x; 1.9467x over previous
//
#include <hip/hip_runtime.h>
#include <hip/hip_bf16.h>

#define NN 64
#define CI 128
#define HD 128
#define KC 5
#define SXS 136   // sx row stride in halfwords: 272 B, 16B-aligned, +8 pad for bank rotation

typedef float v4f __attribute__((ext_vector_type(4)));
typedef __bf16 v8bf __attribute__((ext_vector_type(8)));
typedef unsigned short us8 __attribute__((ext_vector_type(8)));

__device__ __forceinline__ float us2f(unsigned short u) {
    union { unsigned i; float f; } v; v.i = ((unsigned)u) << 16; return v.f;
}
__device__ __forceinline__ unsigned short f2us(float f) {
    __hip_bfloat16 h = __float2bfloat16(f);
    return *reinterpret_cast<unsigned short*>(&h);
}

// ---------------- pre-kernel: weights-only folding ----------------
// z[h] = sum_c W2[h][c] * Wl[c]   -> ws[0..128)
// ws[128] = b1 . z ; ws[129] = b2 . Wl
extern "C" __global__ void zprep_kernel(const float* __restrict__ W2,
                                        const float* __restrict__ Wl,
                                        const float* __restrict__ b1,
                                        const float* __restrict__ b2,
                                        float* __restrict__ ws)
{
    __shared__ float r1[2], r2[2];
    const int t = threadIdx.x;   // 128 threads
    float a = 0.f;
    for (int c = 0; c < HD; ++c) a += W2[t * HD + c] * Wl[c];
    ws[t] = a;
    float p1 = b1[t] * a;
    float p2 = b2[t] * Wl[t];
    #pragma unroll
    for (int off = 32; off; off >>= 1) {
        p1 += __shfl_down(p1, off, 64);
        p2 += __shfl_down(p2, off, 64);
    }
    if ((t & 63) == 0) { r1[t >> 6] = p1; r2[t >> 6] = p2; }
    __syncthreads();
    if (t == 0) { ws[HD] = r1[0] + r1[1]; ws[HD + 1] = r2[0] + r2[1]; }
}

// ---------------- main kernel: one block per graph ----------------
extern "C" __global__ __launch_bounds__(256, 2)
void diffpool_main(const float* __restrict__ x,
                   const int* __restrict__ ei,
                   const float* __restrict__ Wp,
                   const float* __restrict__ bp,
                   const float* __restrict__ W1,
                   const float* __restrict__ bl,
                   const float* __restrict__ ws,
                   float* __restrict__ out,
                   int E, int epg)
{
    __shared__ __attribute__((aligned(16))) unsigned short sx[NN][SXS];  // x -> H1 (bf16 bits)
    __shared__ __attribute__((aligned(16))) unsigned short sw1[HD][CI];  // W1^T, XOR-swizzled chunks
    __shared__ int   sadj[NN][NN + 1];  // counts -> float bits; pad 65 kills column conflicts
    __shared__ float sWp[CI * KC];
    __shared__ float sS0[NN][KC];       // S0 = x@Wp
    __shared__ float sS [NN][KC];       // s_pre, then softmaxed s
    __shared__ float sdl[NN][KC];       // s * d
    __shared__ float sd [NN];
    __shared__ float sU [NN][KC];       // adj @ s
    __shared__ float scol[KC];
    __shared__ float sadjp[KC][KC];
    __shared__ float sd2[KC];
    __shared__ float scoef[KC];
    __shared__ float sz[HD];            // z from pre-kernel
    __shared__ float sqp[NN][2];
    __shared__ float sq[NN];            // q[m] = H1[m].z
    __shared__ float sw_[NN];           // w[n] = sum_l coef[l]*sdl[n][l]
    __shared__ float sc0;

    const int t = threadIdx.x;
    const int g = blockIdx.x;
    const int lane = t & 63;
    const int wv = t >> 6;

    // ---- P1: zero adj; stage x (f32->bf16), W1^T (swizzled), Wp, z ----
    {
        int* ap = &sadj[0][0];
        #pragma unroll
        for (int i = 0; i < 17; ++i) {
            int idx = t + 256 * i;
            if (idx < NN * (NN + 1)) ap[idx] = 0;
        }
    }
    {
        const float* xg = x + (size_t)g * (NN * CI);
        #pragma unroll
        for (int i = 0; i < 4; ++i) {
            int idx = t + 256 * i;           // 1024 chunks = 64 rows x 16
            int row = idx >> 4, ch = idx & 15;
            const float4 v0 = *reinterpret_cast<const float4*>(xg + row * CI + ch * 8);
            const float4 v1 = *reinterpret_cast<const float4*>(xg + row * CI + ch * 8 + 4);
            us8 pk;
            pk[0] = f2us(v0.x); pk[1] = f2us(v0.y); pk[2] = f2us(v0.z); pk[3] = f2us(v0.w);
            pk[4] = f2us(v1.x); pk[5] = f2us(v1.y); pk[6] = f2us(v1.z); pk[7] = f2us(v1.w);
            *reinterpret_cast<us8*>(&sx[row][ch * 8]) = pk;
        }
    }
    {
        #pragma unroll
        for (int i = 0; i < 8; ++i) {
            int idx = t + 256 * i;           // 2048 = 128 cols(n) x 16 k-chunks
            int n = idx & 127, k8 = idx >> 7;
            us8 pk;
            #pragma unroll
            for (int j = 0; j < 8; ++j)
                pk[j] = f2us(W1[(k8 * 8 + j) * HD + n]);
            int sc = (k8 ^ (n & 15)) * 8;    // XOR swizzle spreads banks
            *reinterpret_cast<us8*>(&sw1[n][sc]) = pk;
        }
    }
    #pragma unroll
    for (int i = 0; i < 3; ++i) {
        int idx = t + 256 * i;
        if (idx < CI * KC) sWp[idx] = Wp[idx];
    }
    if (t < 32) *reinterpret_cast<float4*>(&sz[t * 4]) = reinterpret_cast<const float4*>(ws)[t];
    __syncthreads();

    // ---- P2: adjacency counts via LDS atomics ----
    {
        const int base = g * epg;
        for (int j = t; j < epg; j += 256) {
            int sn = ei[base + j] & 63;
            int dn = ei[E + base + j] & 63;
            atomicAdd(&sadj[sn][dn], 1);
        }
    }
    __syncthreads();

    // ---- P3: int counts -> float bits in place ----
    {
        int* ap = &sadj[0][0];
        #pragma unroll
        for (int i = 0; i < 17; ++i) {
            int idx = t + 256 * i;
            if (idx < NN * (NN + 1)) ap[idx] = __float_as_int((float)ap[idx]);
        }
    }
    __syncthreads();
    #define ADJF(n, m) __int_as_float(sadj[n][m])

    // ---- P4: S0 = x@Wp ; degrees d ----
    for (int o = t; o < NN * KC; o += 256) {
        int n = o / KC, c = o % KC;
        float a = 0.f;
        const unsigned short* xr = &sx[n][0];
        for (int k = 0; k < CI; ++k) a += us2f(xr[k]) * sWp[k * KC + c];
        sS0[n][c] = a;
    }
    if (t < NN) {
        float s_ = 0.f;
        for (int m = 0; m < NN; ++m) s_ += ADJF(t, m);
        s_ += 1.0f - ADJF(t, t);
        sd[t] = rsqrtf(fmaxf(s_, 1.0f));
    }
    __syncthreads();

    // ---- P5: H1 = x@W1 via MFMA (writeback into sx, wave-private rows) + s_pre ----
    {
        const int m16 = lane & 15;
        const int q = lane >> 4;            // 0..3
        const int arow = wv * 16 + m16;
        v8bf afrag[4];
        #pragma unroll
        for (int ks = 0; ks < 4; ++ks)
            afrag[ks] = *reinterpret_cast<const v8bf*>(&sx[arow][ks * 32 + q * 8]);
        v4f acc[8];
        #pragma unroll
        for (int ct = 0; ct < 8; ++ct)
            #pragma unroll
            for (int r = 0; r < 4; ++r) acc[ct][r] = 0.f;
        #pragma unroll
        for (int ct = 0; ct < 8; ++ct) {
            const int bn = ct * 16 + m16;
            #pragma unroll
            for (int ks = 0; ks < 4; ++ks) {
                int ch = (ks * 4 + q) ^ m16;
                v8bf bfrag = *reinterpret_cast<const v8bf*>(&sw1[bn][ch * 8]);
                acc[ct] = __builtin_amdgcn_mfma_f32_16x16x32_bf16(afrag[ks], bfrag, acc[ct], 0, 0, 0);
            }
        }
        #pragma unroll
        for (int ct = 0; ct < 8; ++ct)
            #pragma unroll
            for (int r = 0; r < 4; ++r)
                sx[wv * 16 + q * 4 + r][ct * 16 + m16] = f2us(acc[ct][r]);
    }
    // s_pre[n][j] = d[n] * sum_m adjl[n][m]*d[m]*S0[m][j] + bp[j]
    for (int o = t; o < NN * KC; o += 256) {
        int n = o / KC, j = o % KC;
        float a = 0.f;
        for (int m = 0; m < NN; ++m) {
            float al = (m == n) ? 1.0f : ADJF(n, m);
            a += al * (sd[m] * sS0[m][j]);
        }
        sS[n][j] = a * sd[n] + bp[j];
    }
    __syncthreads();

    // ---- P6: softmax over 5 clusters ----
    if (t < NN) {
        const float dn = sd[t];
        float v0 = sS[t][0], v1 = sS[t][1], v2 = sS[t][2], v3 = sS[t][3], v4 = sS[t][4];
        float mx = fmaxf(fmaxf(fmaxf(v0, v1), fmaxf(v2, v3)), v4);
        v0 = expf(v0 - mx); v1 = expf(v1 - mx); v2 = expf(v2 - mx);
        v3 = expf(v3 - mx); v4 = expf(v4 - mx);
        float inv = 1.0f / (v0 + v1 + v2 + v3 + v4);
        v0 *= inv; v1 *= inv; v2 *= inv; v3 *= inv; v4 *= inv;
        sS[t][0] = v0; sS[t][1] = v1; sS[t][2] = v2; sS[t][3] = v3; sS[t][4] = v4;
        sdl[t][0] = v0 * dn; sdl[t][1] = v1 * dn; sdl[t][2] = v2 * dn;
        sdl[t][3] = v3 * dn; sdl[t][4] = v4 * dn;
    }
    __syncthreads();

    // ---- P7: U = adj @ s (raw adj) ; scol ----
    for (int o = t; o < NN * KC; o += 256) {
        int n = o / KC, l = o % KC;
        float a = 0.f;
        for (int m = 0; m < NN; ++m) a += ADJF(n, m) * sS[m][l];
        sU[n][l] = a;
    }
    if (t >= 64 && t < 64 + KC) {
        int k = t - 64;
        float c_ = 0.f;
        for (int n = 0; n < NN; ++n) c_ += sS[n][k];
        scol[k] = c_;
    }
    __syncthreads();

    // ---- P8: adjp = s^T U ; q-partials q[m] = H1[m].z ----
    if (t < KC * KC) {
        int k = t / KC, l = t % KC;
        float a = 0.f;
        for (int n = 0; n < NN; ++n) a += sS[n][k] * sU[n][l];
        sadjp[k][l] = a;
    }
    if (t >= 64 && t < 192) {
        int m = (t - 64) >> 1, p = t & 1;
        float a = 0.f;
        const unsigned short* hr = &sx[m][p * 64];
        const float* zp = &sz[p * 64];
        for (int j = 0; j < 64; ++j) a += us2f(hr[j]) * zp[j];
        sqp[m][p] = a;
    }
    __syncthreads();

    // ---- P9: q final ; d2 ----
    if (t < NN) {
        sq[t] = sqp[t][0] + sqp[t][1];
    } else if (t < NN + KC) {
        int k = t - NN;
        float s_ = 0.f;
        #pragma unroll
        for (int l = 0; l < KC; ++l) s_ += sadjp[k][l];
        s_ += 1.0f - sadjp[k][k];
        sd2[k] = rsqrtf(fmaxf(s_, 1.0f));
    }
    __syncthreads();

    // ---- P10: coef[l] = d2[l] * sum_k d2[k]*adjl2[k][l] ----
    if (t < KC) {
        float a = 0.f;
        #pragma unroll
        for (int k = 0; k < KC; ++k) a += sd2[k] * sadjp[k][t];
        a += sd2[t] * (1.0f - sadjp[t][t]);
        scoef[t] = sd2[t] * a;
    }
    __syncthreads();

    // ---- P11: w[n] = sum_l coef[l]*sdl[n][l] ; c0 = coef.scol ----
    if (t < NN) {
        float a = 0.f;
        #pragma unroll
        for (int l = 0; l < KC; ++l) a += scoef[l] * sdl[t][l];
        sw_[t] = a;
    } else if (t == NN) {
        float a = 0.f;
        #pragma unroll
        for (int l = 0; l < KC; ++l) a += scoef[l] * scol[l];
        sc0 = a;
    }
    __syncthreads();

    // ---- P12: u[m] = d[m]*sum_n w[n]*adjl[n][m]; out = u.q + c0*b1z + 5*b2wl + bl ----
    if (t < NN) {
        float a = 0.f;
        for (int n = 0; n < NN; ++n) {
            float al = (n == t) ? 1.0f : ADJF(n, t);
            a += sw_[n] * al;
        }
        float v = sd[t] * a * sq[t];
        #pragma unroll
        for (int off = 32; off; off >>= 1) v += __shfl_down(v, off, 64);
        if (t == 0)
            out[g] = v + sc0 * ws[HD] + 5.0f * ws[HD + 1] + bl[0];
    }
}

extern "C" void kernel_launch(void* const* d_in, const int* in_sizes, int n_in,
                              void* d_out, int out_size, void* d_ws, size_t ws_size,
                              hipStream_t stream) {
    const float* x  = (const float*)d_in[0];
    const int*   ei = (const int*)d_in[1];
    // d_in[2] = batch (layout implied; unused)
    const float* Wp = (const float*)d_in[3];
    const float* bp = (const float*)d_in[4];
    const float* W1 = (const float*)d_in[5];
    const float* b1 = (const float*)d_in[6];
    const float* W2 = (const float*)d_in[7];
    const float* b2 = (const float*)d_in[8];
    const float* Wl = (const float*)d_in[9];
    const float* bl = (const float*)d_in[10];
    float* out = (float*)d_out;
    float* ws  = (float*)d_ws;

    const int B = out_size;            // 8192 graphs
    const int E = in_sizes[1] / 2;     // edge_index is [2, E]
    const int epg = E / B;             // 512 edges per graph

    zprep_kernel<<<1, 128, 0, stream>>>(W2, Wl, b1, b2, ws);
    diffpool_main<<<B, 256, 0, stream>>>(x, ei, Wp, bp, W1, bl, ws, out, E, epg);
}

// Round 4
// 491.774 us; speedup vs baseline: 2.4493x; 1.2582x over previous
//
#include <hip/hip_runtime.h>
#include <hip/hip_bf16.h>

#define NN 64
#define CI 128
#define HD 128
#define KC 5
#define SXS 136   // sx row stride in halfwords: 272 B = 68 dwords == 4 mod 32 banks -> conflict-free MFMA frag reads

// ws layout (floats): [0,9216) Wpk B-fragments (36 frags x 64 lanes x 8 bf16 = 36864 B)
//                     [9216,9344) z = W2 @ Wl ; ws[9344] = b1.z ; ws[9345] = b2.Wl
#define WS_Z   9216
#define WS_B1Z 9344
#define WS_B2W 9345

typedef float v4f __attribute__((ext_vector_type(4)));
typedef __bf16 v8bf __attribute__((ext_vector_type(8)));
typedef unsigned short us8 __attribute__((ext_vector_type(8)));

__device__ __forceinline__ float us2f(unsigned short u) {
    union { unsigned i; float f; } v; v.i = ((unsigned)u) << 16; return v.f;
}
__device__ __forceinline__ unsigned short f2us(float f) {
    __hip_bfloat16 h = __float2bfloat16(f);
    return *reinterpret_cast<unsigned short*>(&h);
}

// ---------------- pre-kernel: weights-only folding + B-fragment packing ----------------
extern "C" __global__ void zprep(const float* __restrict__ W1,
                                 const float* __restrict__ Wp,
                                 const float* __restrict__ W2,
                                 const float* __restrict__ Wl,
                                 const float* __restrict__ b1,
                                 const float* __restrict__ b2,
                                 float* __restrict__ ws)
{
    const int b = blockIdx.x, t = threadIdx.x;   // 64 threads
    if (b < 36) {
        // fragment f = b: ct = f>>2 (column tile), ks = f&3 (k-slice of 32)
        // B-lane mapping (verified R3): n = ct*16 + (lane&15), k = ks*32 + (lane>>4)*8 + j
        const int ct = b >> 2, ks = b & 3;
        const int q = t >> 4, m16 = t & 15;
        const int k0 = ks * 32 + q * 8;
        us8 pk;
        #pragma unroll
        for (int j = 0; j < 8; ++j) {
            const int k = k0 + j;
            float v;
            if (ct < 8)      v = W1[k * HD + ct * 16 + m16];
            else             v = (m16 < KC) ? Wp[k * KC + m16] : 0.f;
            pk[j] = f2us(v);
        }
        reinterpret_cast<us8*>(ws)[b * 64 + t] = pk;
    } else if (b == 36) {
        float a0 = 0.f, a1 = 0.f;
        for (int c = 0; c < HD; ++c) {
            const float wl = Wl[c];
            a0 += W2[t * HD + c] * wl;
            a1 += W2[(t + 64) * HD + c] * wl;
        }
        ws[WS_Z + t] = a0;
        ws[WS_Z + 64 + t] = a1;
        float p1 = b1[t] * a0 + b1[t + 64] * a1;
        float p2 = b2[t] * Wl[t] + b2[t + 64] * Wl[t + 64];
        #pragma unroll
        for (int off = 32; off; off >>= 1) {
            p1 += __shfl_down(p1, off, 64);
            p2 += __shfl_down(p2, off, 64);
        }
        if (t == 0) { ws[WS_B1Z] = p1; ws[WS_B2W] = p2; }
    }
}

// ---------------- main kernel: one block per graph, 4 blocks/CU ----------------
extern "C" __global__ __launch_bounds__(256, 4)
void diffpool_main(const float* __restrict__ x,
                   const int* __restrict__ ei,
                   const float* __restrict__ bp,
                   const float* __restrict__ bl,
                   const float* __restrict__ ws,
                   float* __restrict__ out,
                   int E, int epg)
{
    __shared__ __attribute__((aligned(16))) unsigned short sx[NN][SXS]; // x -> H1 (bf16 bits)
    __shared__ int   sadj[NN][NN + 1];  // raw int counts; pad 65 kills column conflicts
    __shared__ float sS0[NN][KC];       // S0 = x@Wp (from MFMA tile 8)
    __shared__ float sS [NN][KC];       // softmaxed s
    __shared__ float sU [NN][KC];       // adj @ s
    __shared__ float sd [NN];           // d = rsqrt(deg_l)
    __shared__ float sz [HD];           // z = W2@Wl
    __shared__ float sqp[2][NN];        // q partials
    __shared__ float sw_[NN];           // w[n] = d[n] * (s[n].coef)
    __shared__ float sadjp[25];
    __shared__ float sd2[KC];
    __shared__ float scoef[KC];

    const int t = threadIdx.x;
    const int g = blockIdx.x;
    const int lane = t & 63;
    const int wv = t >> 6;

    // ---- P1: zero adj; stage x (f32->bf16); load z ----
    {
        int* ap = &sadj[0][0];
        for (int i = t; i < NN * (NN + 1); i += 256) ap[i] = 0;
        const float* xg = x + (size_t)g * (NN * CI);
        #pragma unroll
        for (int i = 0; i < 4; ++i) {
            const int idx = t + 256 * i;          // 1024 chunks = 64 rows x 16
            const int row = idx >> 4, ch = idx & 15;
            const float4 v0 = *reinterpret_cast<const float4*>(xg + row * CI + ch * 8);
            const float4 v1 = *reinterpret_cast<const float4*>(xg + row * CI + ch * 8 + 4);
            us8 pk;
            pk[0] = f2us(v0.x); pk[1] = f2us(v0.y); pk[2] = f2us(v0.z); pk[3] = f2us(v0.w);
            pk[4] = f2us(v1.x); pk[5] = f2us(v1.y); pk[6] = f2us(v1.z); pk[7] = f2us(v1.w);
            *reinterpret_cast<us8*>(&sx[row][ch * 8]) = pk;
        }
        if (t < 32)
            reinterpret_cast<float4*>(sz)[t] = reinterpret_cast<const float4*>(ws + WS_Z)[t];
    }
    __syncthreads();

    // ---- P2: adjacency counts via LDS atomics ----
    {
        const int base = g * epg;
        for (int j = t; j < epg; j += 256) {
            const int sn = ei[base + j] & 63;
            const int dn = ei[E + base + j] & 63;
            atomicAdd(&sadj[sn][dn], 1);
        }
    }
    __syncthreads();

    // ---- P3: MFMA [H1|S0] = x @ [W1|Wp'] ; degrees d ----
    {
        const int m16 = lane & 15;
        const int q = lane >> 4;
        const int arow = wv * 16 + m16;
        v8bf afrag[4];
        #pragma unroll
        for (int ks = 0; ks < 4; ++ks)
            afrag[ks] = *reinterpret_cast<const v8bf*>(&sx[arow][ks * 32 + q * 8]);
        const v8bf* wpk = reinterpret_cast<const v8bf*>(ws);
        #pragma unroll
        for (int ct = 0; ct < 9; ++ct) {
            v4f acc = {0.f, 0.f, 0.f, 0.f};
            #pragma unroll
            for (int ks = 0; ks < 4; ++ks) {
                const v8bf bfrag = wpk[(ct * 4 + ks) * 64 + lane];
                acc = __builtin_amdgcn_mfma_f32_16x16x32_bf16(afrag[ks], bfrag, acc, 0, 0, 0);
            }
            // C/D: col = lane&15, row = q*4 + r (verified R3)
            if (ct < 8) {
                #pragma unroll
                for (int r = 0; r < 4; ++r)
                    sx[wv * 16 + q * 4 + r][ct * 16 + m16] = f2us(acc[r]);
            } else if (m16 < KC) {
                #pragma unroll
                for (int r = 0; r < 4; ++r)
                    sS0[wv * 16 + q * 4 + r][m16] = acc[r];
            }
        }
    }
    if (t < NN) {
        int si = 0;
        for (int m = 0; m < NN; ++m) si += sadj[t][m];
        const int deg = si + 1 - sadj[t][t];     // diag set to 1; deg >= 1 always
        sd[t] = rsqrtf((float)deg);
    }
    __syncthreads();

    float sv0 = 0.f, sv1 = 0.f, sv2 = 0.f, sv3 = 0.f, sv4 = 0.f; // wave0: s[n][:] in regs

    // ---- P4: wave0 = s_pre+softmax+U+adjp+d2+coef+w (wave-internal LDS ordering);
    //          waves1,2 = q partials ----
    if (wv == 0) {
        const int n = lane;
        const float dn = sd[n];
        // s_pre
        float a0 = 0.f, a1 = 0.f, a2 = 0.f, a3 = 0.f, a4 = 0.f;
        for (int m = 0; m < NN; ++m) {
            const float al = (m == n) ? 1.f : (float)sadj[n][m];
            const float f = al * sd[m];
            a0 += f * sS0[m][0]; a1 += f * sS0[m][1]; a2 += f * sS0[m][2];
            a3 += f * sS0[m][3]; a4 += f * sS0[m][4];
        }
        a0 = a0 * dn + bp[0]; a1 = a1 * dn + bp[1]; a2 = a2 * dn + bp[2];
        a3 = a3 * dn + bp[3]; a4 = a4 * dn + bp[4];
        const float mx = fmaxf(fmaxf(fmaxf(a0, a1), fmaxf(a2, a3)), a4);
        a0 = expf(a0 - mx); a1 = expf(a1 - mx); a2 = expf(a2 - mx);
        a3 = expf(a3 - mx); a4 = expf(a4 - mx);
        const float inv = 1.f / (a0 + a1 + a2 + a3 + a4);
        sv0 = a0 * inv; sv1 = a1 * inv; sv2 = a2 * inv; sv3 = a3 * inv; sv4 = a4 * inv;
        sS[n][0] = sv0; sS[n][1] = sv1; sS[n][2] = sv2; sS[n][3] = sv3; sS[n][4] = sv4;
        // U = adj @ s (raw adj) — reads sS written by this wave (in-order LDS)
        float u0 = 0.f, u1 = 0.f, u2 = 0.f, u3 = 0.f, u4 = 0.f;
        for (int m = 0; m < NN; ++m) {
            const float a = (float)sadj[n][m];
            u0 += a * sS[m][0]; u1 += a * sS[m][1]; u2 += a * sS[m][2];
            u3 += a * sS[m][3]; u4 += a * sS[m][4];
        }
        sU[n][0] = u0; sU[n][1] = u1; sU[n][2] = u2; sU[n][3] = u3; sU[n][4] = u4;
        // adjp = s^T U
        if (n < 25) {
            const int k = n / 5, l = n % 5;
            float a = 0.f;
            for (int mm = 0; mm < NN; ++mm) a += sS[mm][k] * sU[mm][l];
            sadjp[n] = a;
        }
        // d2
        if (n < KC) {
            float s_ = 0.f;
            #pragma unroll
            for (int l = 0; l < KC; ++l) s_ += sadjp[n * 5 + l];
            s_ += 1.f - sadjp[n * 6];
            sd2[n] = rsqrtf(fmaxf(s_, 1.f));
        }
        // coef[l] = d2[l] * (sum_k d2[k]*adjl2[k][l]), adjl2 diag set to 1
        if (n < KC) {
            float a = 0.f;
            #pragma unroll
            for (int k = 0; k < KC; ++k) a += sd2[k] * sadjp[k * 5 + n];
            a += sd2[n] * (1.f - sadjp[n * 6]);
            scoef[n] = sd2[n] * a;
        }
        // w[n] = d[n] * (s[n] . coef)
        const float wn = dn * (scoef[0] * sv0 + scoef[1] * sv1 + scoef[2] * sv2 +
                               scoef[3] * sv3 + scoef[4] * sv4);
        sw_[n] = wn;
    } else if (wv <= 2) {
        // q partials: q[m] = H1[m] . z over half the columns
        const int p = wv - 1, m = lane;
        float a = 0.f;
        #pragma unroll
        for (int c = 0; c < 8; ++c) {
            const us8 h = *reinterpret_cast<const us8*>(&sx[m][p * 64 + c * 8]);
            #pragma unroll
            for (int j = 0; j < 8; ++j) a += us2f(h[j]) * sz[p * 64 + c * 8 + j];
        }
        sqp[p][m] = a;
    }
    __syncthreads();

    // ---- P5: wave0: u = d ⊙ (adj_l^T w); out = u.q + c0*b1z + 5*b2wl + bl ----
    if (wv == 0) {
        const int m = lane;
        float a = 0.f;
        for (int n = 0; n < NN; ++n) {
            const float al = (n == m) ? 1.f : (float)sadj[n][m];
            a += sw_[n] * al;
        }
        const float qm = sqp[0][m] + sqp[1][m];
        float v = sd[m] * a * qm;
        // c0*b1z = sum_m (s[m].coef) * b1z, folded per-lane
        v += (scoef[0] * sv0 + scoef[1] * sv1 + scoef[2] * sv2 +
              scoef[3] * sv3 + scoef[4] * sv4) * ws[WS_B1Z];
        #pragma unroll
        for (int off = 32; off; off >>= 1) v += __shfl_down(v, off, 64);
        if (lane == 0)
            out[g] = v + 5.f * ws[WS_B2W] + bl[0];
    }
}

extern "C" void kernel_launch(void* const* d_in, const int* in_sizes, int n_in,
                              void* d_out, int out_size, void* d_ws, size_t ws_size,
                              hipStream_t stream) {
    const float* x  = (const float*)d_in[0];
    const int*   ei = (const int*)d_in[1];
    // d_in[2] = batch (layout implied; unused)
    const float* Wp = (const float*)d_in[3];
    const float* bp = (const float*)d_in[4];
    const float* W1 = (const float*)d_in[5];
    const float* b1 = (const float*)d_in[6];
    const float* W2 = (const float*)d_in[7];
    const float* b2 = (const float*)d_in[8];
    const float* Wl = (const float*)d_in[9];
    const float* bl = (const float*)d_in[10];
    float* out = (float*)d_out;
    float* ws  = (float*)d_ws;

    const int B = out_size;            // 8192 graphs
    const int E = in_sizes[1] / 2;     // edge_index is [2, E]
    const int epg = E / B;             // 512 edges per graph

    zprep<<<37, 64, 0, stream>>>(W1, Wp, W2, Wl, b1, b2, ws);
    diffpool_main<<<B, 256, 0, stream>>>(x, ei, bp, bl, ws, out, E, epg);
}